// Round 12
// baseline (211.436 us; speedup 1.0000x reference)
//
#include <hip/hip_runtime.h>
#include <math.h>

// ---------------------------------------------------------------------------
// GCN (EdgeConv x3 + classifier + log_softmax) on MI355X.
// R12: "S-precombine" — h1_gemm's MFMA epilogue now emits
//   S[n][c] = deg*(ai2+b2) + aj2_self + We2@eagg   (fp16)
// so gather2 is just r = relu(S[n] + sum_e AJ2[src]) + U/Z projection
// (drops AI2 12.8MB round-trip and 6 global loads/node + sWe/b2 staging).
// Kept: R11 h1+GEMM fusion (LDS h1 tile, stride 144), W2bf global bf16,
// mid_fused, split CSR build (pos precomputed), packed CSR uint2, fp16 AJ2
// + v_pk_add_f16 gather, xpad, collapsed layer 3.
// Harness d_ws 256MiB poison fill (~45us) is fixed cost.
// ---------------------------------------------------------------------------

static inline size_t align256(size_t x) { return (x + 255) & ~size_t(255); }

typedef unsigned short ushort_t;
using frag8  = __attribute__((ext_vector_type(8))) short;     // 8 bf16 (4 VGPR)
using f32x4v = __attribute__((ext_vector_type(4))) float;     // 4 fp32 acc
using half8  = __attribute__((ext_vector_type(8))) _Float16;  // 8 fp16

__device__ inline unsigned short f2bf(float f) {
    unsigned u = __float_as_uint(f);
    unsigned r = (u + 0x7fffu + ((u >> 16) & 1u)) >> 16;
    return (unsigned short)r;
}
__device__ inline float bflo(unsigned u) { return __uint_as_float(u << 16); }
__device__ inline float bfhi(unsigned u) { return __uint_as_float(u & 0xffff0000u); }

// ---- CSR build ------------------------------------------------------------

__global__ __launch_bounds__(256) void build_count(
    const int* __restrict__ ei, int* __restrict__ count,
    int* __restrict__ pos, int E)
{
    int e4 = (blockIdx.x * 256 + threadIdx.x) * 4;
    if (e4 >= E) return;
    if (e4 + 3 < E) {
        int4 d = *(const int4*)(ei + E + e4);
        int4 po;
        po.x = atomicAdd(&count[d.x], 1);
        po.y = atomicAdd(&count[d.y], 1);
        po.z = atomicAdd(&count[d.z], 1);
        po.w = atomicAdd(&count[d.w], 1);
        *(int4*)(pos + e4) = po;
    } else {
        for (int e = e4; e < E; ++e)
            pos[e] = atomicAdd(&count[ei[E + e]], 1);
    }
}

__global__ __launch_bounds__(256) void scan_pass1(
    const int* __restrict__ count, int* __restrict__ rowstart,
    int* __restrict__ bsum, int n)
{
    __shared__ int sh[256];
    const int tid = threadIdx.x;
    const int base = blockIdx.x * 1024 + tid * 4;
    int v0 = 0, v1 = 0, v2 = 0, v3 = 0;
    if (base + 3 < n) {
        int4 c = *(const int4*)(count + base);
        v0 = c.x; v1 = c.y; v2 = c.z; v3 = c.w;
    } else {
        if (base + 0 < n) v0 = count[base + 0];
        if (base + 1 < n) v1 = count[base + 1];
        if (base + 2 < n) v2 = count[base + 2];
        if (base + 3 < n) v3 = count[base + 3];
    }
    int tsum = v0 + v1 + v2 + v3;
    sh[tid] = tsum;
    __syncthreads();
    for (int off = 1; off < 256; off <<= 1) {
        int t = (tid >= off) ? sh[tid - off] : 0;
        __syncthreads();
        sh[tid] += t;
        __syncthreads();
    }
    int excl = sh[tid] - tsum;
    int p0 = excl + v0, p1 = p0 + v1, p2 = p1 + v2, p3 = p2 + v3;
    if (base + 0 < n) rowstart[base + 1] = p0;
    if (base + 1 < n) rowstart[base + 2] = p1;
    if (base + 2 < n) rowstart[base + 3] = p2;
    if (base + 3 < n) rowstart[base + 4] = p3;
    if (tid == 255) bsum[blockIdx.x] = sh[255];
}

// mid_fused: block 0 = scan_pass2; block 1 = collapsed layer-3 prep;
// blocks 2-5 = W2 -> bf16 [col][k] global buffer (32 KB).
__global__ __launch_bounds__(256) void mid_fused(
    const int* __restrict__ bsum, int* __restrict__ bexcl, int nb,
    const float* __restrict__ W3, const float* __restrict__ b3,
    const float* __restrict__ Wc, const float* __restrict__ bc,
    float* __restrict__ AB, float* __restrict__ consts,
    const float* __restrict__ W2, ushort_t* __restrict__ W2bf)
{
    const int t = threadIdx.x;
    if (blockIdx.x == 0) {
        if (t < 64) {
            int own = (t < nb) ? bsum[t] : 0;
            int x = own;
            for (int off = 1; off < 64; off <<= 1) {
                int s = __shfl_up(x, off);
                if (t >= off) x += s;
            }
            bexcl[t] = x - own;
        }
    } else if (blockIdx.x == 1) {
        for (int idx = t; idx < 512; idx += 256) {
            int j = idx >> 6, k = idx & 63;
            int jj = j & 3;
            int base = (j >= 4) ? 64 : 0;
            float s = 0.f;
            #pragma unroll
            for (int c = 0; c < 32; ++c)
                s += Wc[jj * 32 + c] * W3[c * 131 + base + k];
            AB[idx] = s;
        }
        if (t < 4) {
            float db = 0.f;
            for (int c = 0; c < 32; ++c) db += Wc[t * 32 + c] * b3[c];
            consts[t] = db;
            consts[4 + t] = bc[t];
            for (int q = 0; q < 3; ++q) {
                float s = 0.f;
                for (int c = 0; c < 32; ++c) s += Wc[t * 32 + c] * W3[c * 131 + 128 + q];
                consts[8 + t * 3 + q] = s;
            }
        }
    } else {
        int i0 = (blockIdx.x - 2) * 4096 + t;
        int i1 = (blockIdx.x - 1) * 4096;
        for (int idx = i0; idx < i1; idx += 256) {
            int jg = idx >> 7, k = idx & 127;
            float w = (jg < 64) ? W2[jg * 259 + k] : W2[(jg - 64) * 259 + 128 + k];
            W2bf[idx] = f2bf(w);
        }
    }
}

// pass3: finalize rowstart; also emit xpad float4 table
__global__ __launch_bounds__(256) void scan_pass3(
    int* __restrict__ rowstart, const int* __restrict__ bexcl,
    const float* __restrict__ x, float4* __restrict__ xpad, int n)
{
    int j = blockIdx.x * 256 + threadIdx.x;
    if (j > n) return;
    if (j == 0) {
        rowstart[0] = 0;
    } else {
        int b = (j - 1) >> 10;
        if (b > 0) rowstart[j] += bexcl[b];
    }
    if (j < n)
        xpad[j] = make_float4(x[j * 3], x[j * 3 + 1], x[j * 3 + 2], 0.f);
}

// scatter packed edge record: {bf16 e0 | bf16 e1 << 16, bf16 e2 | src << 16}
__global__ __launch_bounds__(256) void csr_scatter(
    const int* __restrict__ ei, const float* __restrict__ ea,
    const int* __restrict__ pos, const int* __restrict__ rowstart,
    uint2* __restrict__ csrp, int E)
{
    int e4 = (blockIdx.x * 256 + threadIdx.x) * 4;
    if (e4 >= E) return;
    if (e4 + 3 < E) {
        int4 s = *(const int4*)(ei + e4);
        int4 d = *(const int4*)(ei + E + e4);
        int4 po = *(const int4*)(pos + e4);
        float4 a = *(const float4*)(ea + (size_t)e4 * 3);
        float4 b = *(const float4*)(ea + (size_t)e4 * 3 + 4);
        float4 c = *(const float4*)(ea + (size_t)e4 * 3 + 8);
        float ev[12] = { a.x, a.y, a.z, a.w, b.x, b.y, b.z, b.w, c.x, c.y, c.z, c.w };
        int sv[4] = { s.x, s.y, s.z, s.w };
        int dv[4] = { d.x, d.y, d.z, d.w };
        int pv[4] = { po.x, po.y, po.z, po.w };
        #pragma unroll
        for (int r = 0; r < 4; ++r) {
            uint2 p;
            p.x = (unsigned)f2bf(ev[r * 3 + 0]) | ((unsigned)f2bf(ev[r * 3 + 1]) << 16);
            p.y = (unsigned)f2bf(ev[r * 3 + 2]) | ((unsigned)sv[r] << 16);
            csrp[rowstart[dv[r]] + pv[r]] = p;
        }
    } else {
        for (int e = e4; e < E; ++e) {
            uint2 p;
            p.x = (unsigned)f2bf(ea[e * 3 + 0]) | ((unsigned)f2bf(ea[e * 3 + 1]) << 16);
            p.y = (unsigned)f2bf(ea[e * 3 + 2]) | ((unsigned)ei[e] << 16);
            csrp[rowstart[ei[E + e]] + pos[e]] = p;
        }
    }
}

// ---- fused layer-1 + layer-2 GEMM + self-epilogue -------------------------
// Block = 64 nodes. Phase 1: 8 lanes/node edge aggregation + 10->128 matvec,
// h1 (bf16) -> LDS tile (stride 144 ushorts); deg/eagg stashed in LDS.
// Phase 2: MFMA 16x16x32_bf16 (A from LDS, B from global W2bf), epilogue
// emits AJ2 = aj2 (fp16) and S = deg*(ai2+b2)+aj2_self+We2@eagg (fp16).

__global__ __launch_bounds__(256) void h1_gemm(
    const float4* __restrict__ xpad, const float* __restrict__ W1,
    const float* __restrict__ b1, const float* __restrict__ W2,
    const float* __restrict__ b2, const int* __restrict__ rowstart,
    const uint2* __restrict__ csrp, float4* __restrict__ eagg4,
    const ushort_t* __restrict__ W2bf,
    _Float16* __restrict__ S, _Float16* __restrict__ AJ2, int n_nodes)
{
    constexpr int HS = 144;                 // LDS h1 row stride (ushorts)
    __shared__ float sM[10 * 128];
    __shared__ ushort_t sH[64 * HS];
    __shared__ float sWe[192];
    __shared__ float sB2[64];
    __shared__ float sDeg[64];
    __shared__ float4 sE4[64];

    const int tid = threadIdx.x;
    for (int t = tid; t < 1280; t += 256) {
        int k = t >> 7, c = t & 127;
        sM[t] = (k < 9) ? W1[c * 9 + k] : b1[c];
    }
    for (int t = tid; t < 192; t += 256) {
        int c = t / 3, q = t % 3;
        sWe[t] = W2[c * 259 + 256 + q];
    }
    if (tid < 64) sB2[tid] = b2[tid];
    __syncthreads();

    const int base = blockIdx.x * 64;
    const int wave = tid >> 6, wl = tid & 63;
    const int grp = wl >> 3, ch8 = wl & 7;

    // ---- phase 1: two passes of 32 nodes ----
    #pragma unroll
    for (int pass = 0; pass < 2; ++pass) {
        int nl = pass * 32 + wave * 8 + grp;
        int n = base + nl;
        float hv[16];
        if (n < n_nodes) {
            int s0 = rowstart[n], s1 = rowstart[n + 1];
            float xx = 0.f, xy = 0.f, xz = 0.f, ex = 0.f, ey = 0.f, ez = 0.f;
            for (int i = s0 + ch8; i < s1; i += 8) {
                uint2 p = csrp[i];
                int s = (int)(p.y >> 16);
                ex += bflo(p.x); ey += bfhi(p.x); ez += bflo(p.y);
                float4 xv = xpad[s];
                xx += xv.x; xy += xv.y; xz += xv.z;
            }
            #pragma unroll
            for (int off = 1; off < 8; off <<= 1) {
                xx += __shfl_xor(xx, off); xy += __shfl_xor(xy, off); xz += __shfl_xor(xz, off);
                ex += __shfl_xor(ex, off); ey += __shfl_xor(ey, off); ez += __shfl_xor(ez, off);
            }
            float deg = (float)(s1 - s0 + 1);
            float4 xs = xpad[n];
            float v[10] = { deg * xs.x, deg * xs.y, deg * xs.z,
                            xs.x + xx, xs.y + xy, xs.z + xz,
                            ex, ey, ez, deg };
            #pragma unroll
            for (int q = 0; q < 16; ++q) {
                int c = ch8 * 16 + q;
                float h = 0.f;
                #pragma unroll
                for (int k = 0; k < 10; ++k) h += v[k] * sM[k * 128 + c];
                hv[q] = fmaxf(h, 0.f);
            }
            if (ch8 == 0) {
                eagg4[n] = make_float4(ex, ey, ez, 0.f);
                sDeg[nl] = deg;
                sE4[nl] = make_float4(ex, ey, ez, 0.f);
            }
        } else {
            #pragma unroll
            for (int q = 0; q < 16; ++q) hv[q] = 0.f;
            if (ch8 == 0) {
                sDeg[nl] = 1.f;
                sE4[nl] = make_float4(0.f, 0.f, 0.f, 0.f);
            }
        }
        #pragma unroll
        for (int g = 0; g < 2; ++g) {
            uint4 u;
            u.x = (unsigned)f2bf(hv[g * 8 + 0]) | ((unsigned)f2bf(hv[g * 8 + 1]) << 16);
            u.y = (unsigned)f2bf(hv[g * 8 + 2]) | ((unsigned)f2bf(hv[g * 8 + 3]) << 16);
            u.z = (unsigned)f2bf(hv[g * 8 + 4]) | ((unsigned)f2bf(hv[g * 8 + 5]) << 16);
            u.w = (unsigned)f2bf(hv[g * 8 + 6]) | ((unsigned)f2bf(hv[g * 8 + 7]) << 16);
            *(uint4*)(sH + nl * HS + ch8 * 16 + g * 8) = u;
        }
    }
    __syncthreads();

    // ---- phase 2: MFMA + epilogue ----
    const int m = wl & 15, quad = wl >> 4;

    frag8 a[4];
    #pragma unroll
    for (int ks = 0; ks < 4; ++ks)
        a[ks] = *(const frag8*)(sH + (wave * 16 + m) * HS + ks * 32 + quad * 8);

    f32x4v acc[8];
    #pragma unroll
    for (int t = 0; t < 8; ++t) acc[t] = (f32x4v)(0.f);

    #pragma unroll
    for (int t = 0; t < 8; ++t) {
        #pragma unroll
        for (int ks = 0; ks < 4; ++ks) {
            frag8 b = *(const frag8*)(W2bf + (t * 16 + m) * 128 + ks * 32 + quad * 8);
            acc[t] = __builtin_amdgcn_mfma_f32_16x16x32_bf16(a[ks], b, acc[t], 0, 0, 0);
        }
    }

    #pragma unroll
    for (int reg = 0; reg < 4; ++reg) {
        int rloc = wave * 16 + quad * 4 + reg;
        int grow = base + rloc;
        if (grow >= n_nodes) continue;
        float deg = sDeg[rloc];
        float4 e4 = sE4[rloc];
        #pragma unroll
        for (int t = 0; t < 4; ++t) {
            int c = t * 16 + m;
            float we = sWe[c * 3] * e4.x + sWe[c * 3 + 1] * e4.y + sWe[c * 3 + 2] * e4.z;
            float aj = acc[t + 4][reg];
            float sv = deg * (acc[t][reg] + sB2[c]) + aj + we;
            S[(size_t)grow * 64 + c]   = (_Float16)sv;
            AJ2[(size_t)grow * 64 + c] = (_Float16)aj;
        }
    }
}

// ---- layer-2 gather: r = relu(S[n] + sum AJ2[src]); project to U/Z --------

__global__ __launch_bounds__(256) void gather2(
    const _Float16* __restrict__ S, const _Float16* __restrict__ AJ2,
    const int* __restrict__ rowstart, const uint2* __restrict__ csrp,
    const float* __restrict__ AB,
    float* __restrict__ U, float* __restrict__ Z, int n_nodes)
{
    __shared__ float sAB[512];
    const int tid = threadIdx.x;
    for (int t = tid; t < 512; t += 256) sAB[t] = AB[t];
    __syncthreads();

    int wl = tid & 63;
    int grp = wl >> 3, ch8 = wl & 7;
    int n = blockIdx.x * 32 + (tid >> 6) * 8 + grp;
    if (n >= n_nodes) return;

    int s0 = rowstart[n], s1 = rowstart[n + 1];

    half8 hacc0 = (half8)(_Float16)0.f;
    half8 hacc1 = (half8)(_Float16)0.f;
    for (int base = s0; base < s1; base += 8) {
        int j = base + ch8;
        if (j >= s1) j = s1 - 1;            // clamped lanes never consumed
        int myidx = (int)(csrp[j].y >> 16);
        int cnt = s1 - base; if (cnt > 8) cnt = 8;
        #pragma unroll
        for (int k = 0; k < 8; ++k) {
            int s = __shfl(myidx, grp * 8 + k);
            if (k < cnt) {
                half8 v = *(const half8*)(AJ2 + (size_t)s * 64 + ch8 * 8);
                if (k & 1) hacc1 += v; else hacc0 += v;
            }
        }
    }

    half8 sv = *(const half8*)(S + (size_t)n * 64 + ch8 * 8);
    float r[8];
    #pragma unroll
    for (int q = 0; q < 8; ++q)
        r[q] = fmaxf((float)sv[q] + (float)hacc0[q] + (float)hacc1[q], 0.f);

    float pj[8];
    #pragma unroll
    for (int j = 0; j < 8; ++j) {
        float4 wA = *(const float4*)(sAB + j * 64 + ch8 * 8);
        float4 wB = *(const float4*)(sAB + j * 64 + ch8 * 8 + 4);
        pj[j] = r[0] * wA.x + r[1] * wA.y + r[2] * wA.z + r[3] * wA.w
              + r[4] * wB.x + r[5] * wB.y + r[6] * wB.z + r[7] * wB.w;
    }
    #pragma unroll
    for (int off = 1; off < 8; off <<= 1)
        #pragma unroll
        for (int j = 0; j < 8; ++j) pj[j] += __shfl_xor(pj[j], off);

    if (ch8 == 0) {
        *(float4*)(U + (size_t)n * 4) = make_float4(pj[0], pj[1], pj[2], pj[3]);
        *(float4*)(Z + (size_t)n * 4) = make_float4(pj[4], pj[5], pj[6], pj[7]);
    }
}

// ---- final: 8 lanes/node, 8 nodes/wave, sum Z[src] + log_softmax ----------

__global__ __launch_bounds__(256) void final_softmax(
    const float* __restrict__ U, const float* __restrict__ Z,
    const float4* __restrict__ eagg4, const int* __restrict__ rowstart,
    const uint2* __restrict__ csrp, const float* __restrict__ consts,
    float* __restrict__ out, int n_nodes)
{
    int wl = threadIdx.x & 63;
    int grp = wl >> 3, ch8 = wl & 7;
    int n = blockIdx.x * 32 + (threadIdx.x >> 6) * 8 + grp;
    if (n >= n_nodes) return;

    int s0 = rowstart[n], s1 = rowstart[n + 1];
    float ax = 0.f, ay = 0.f, az = 0.f, aw = 0.f;
    for (int i = s0 + ch8; i < s1; i += 8) {
        int s = (int)(csrp[i].y >> 16);
        float4 z = *(const float4*)(Z + (size_t)s * 4);
        ax += z.x; ay += z.y; az += z.z; aw += z.w;
    }
    #pragma unroll
    for (int off = 1; off < 8; off <<= 1) {
        ax += __shfl_xor(ax, off); ay += __shfl_xor(ay, off);
        az += __shfl_xor(az, off); aw += __shfl_xor(aw, off);
    }
    if (ch8 != 0) return;

    float deg = (float)(s1 - s0 + 1);
    float4 u = *(const float4*)(U + (size_t)n * 4);
    float4 zs = *(const float4*)(Z + (size_t)n * 4);   // self-loop term
    float4 e4 = eagg4[n];
    float av[4] = { ax + zs.x, ay + zs.y, az + zs.z, aw + zs.w };
    float uv[4] = { u.x, u.y, u.z, u.w };
    float lg[4];
    #pragma unroll
    for (int j = 0; j < 4; ++j) {
        lg[j] = deg * (uv[j] + consts[j]) + av[j] + consts[4 + j]
              + consts[8 + j * 3] * e4.x + consts[9 + j * 3] * e4.y
              + consts[10 + j * 3] * e4.z;
    }
    float m = fmaxf(fmaxf(lg[0], lg[1]), fmaxf(lg[2], lg[3]));
    float lse = logf(expf(lg[0] - m) + expf(lg[1] - m) + expf(lg[2] - m) + expf(lg[3] - m));
    *(float4*)(out + (size_t)n * 4) =
        make_float4(lg[0] - m - lse, lg[1] - m - lse, lg[2] - m - lse, lg[3] - m - lse);
}

// ---------------------------------------------------------------------------

extern "C" void kernel_launch(void* const* d_in, const int* in_sizes, int n_in,
                              void* d_out, int out_size, void* d_ws, size_t ws_size,
                              hipStream_t stream)
{
    const float* x    = (const float*)d_in[0];
    const int*   ei   = (const int*)  d_in[1];
    const float* ea   = (const float*)d_in[2];
    const float* W1   = (const float*)d_in[3];
    const float* b1   = (const float*)d_in[4];
    const float* W2   = (const float*)d_in[5];
    const float* b2   = (const float*)d_in[6];
    const float* W3   = (const float*)d_in[7];
    const float* b3   = (const float*)d_in[8];
    const float* Wc   = (const float*)d_in[9];
    const float* bc   = (const float*)d_in[10];
    float* out = (float*)d_out;

    const int N = in_sizes[0] / 3;
    const int E = in_sizes[1] / 2;

    char* ws = (char*)d_ws;
    size_t off = 0;
    int*    count    = (int*)(ws + off);            off = align256(off + (size_t)N * 4);
    int*    pos      = (int*)(ws + off);            off = align256(off + (size_t)E * 4);
    int*    rowstart = (int*)(ws + off);            off = align256(off + (size_t)(N + 1) * 4);
    uint2*  csrp     = (uint2*)(ws + off);          off = align256(off + (size_t)E * 8);
    int*    bsum     = (int*)(ws + off);            off = align256(off + 256);
    int*    bexcl    = (int*)(ws + off);            off = align256(off + 256);
    float*  AB       = (float*)(ws + off);          off = align256(off + 512 * 4);
    float*  consts   = (float*)(ws + off);          off = align256(off + 32 * 4);
    ushort_t* W2bf   = (ushort_t*)(ws + off);       off = align256(off + 128 * 128 * 2);
    float4* xpad     = (float4*)(ws + off);         off = align256(off + (size_t)N * 16);
    float4* eagg4    = (float4*)(ws + off);         off = align256(off + (size_t)N * 16);
    _Float16* Sbuf   = (_Float16*)(ws + off);       off = align256(off + (size_t)N * 64 * 2);
    _Float16* AJ2    = (_Float16*)(ws + off);       off = align256(off + (size_t)N * 64 * 2);
    float*  Ubuf     = (float*)(ws + off);          off = align256(off + (size_t)N * 16);
    float*  Zbuf     = (float*)(ws + off);          off = align256(off + (size_t)N * 16);
    (void)ws_size;

    hipMemsetAsync(count, 0, (size_t)N * 4, stream);

    const int eb4 = ((E + 3) / 4 + 255) / 256;
    build_count<<<eb4, 256, 0, stream>>>(ei, count, pos, E);

    const int nb1 = (N + 1023) / 1024;
    scan_pass1<<<nb1, 256, 0, stream>>>(count, rowstart, bsum, N);
    mid_fused<<<6, 256, 0, stream>>>(bsum, bexcl, nb1, W3, b3, Wc, bc, AB, consts, W2, W2bf);
    scan_pass3<<<(N + 1 + 255) / 256, 256, 0, stream>>>(rowstart, bexcl, x, xpad, N);
    csr_scatter<<<eb4, 256, 0, stream>>>(ei, ea, pos, rowstart, csrp, E);

    // fused layer-1 + layer-2 MFMA GEMM + self epilogue (S, AJ2)
    h1_gemm<<<(N + 63) / 64, 256, 0, stream>>>(xpad, W1, b1, W2, b2, rowstart,
                                               csrp, eagg4, W2bf, Sbuf, AJ2, N);

    // layer-2 gather + relu + U/Z projection
    const int gb = (N + 31) / 32;
    gather2<<<gb, 256, 0, stream>>>(Sbuf, AJ2, rowstart, csrp, AB, Ubuf, Zbuf, N);

    // collapsed layer 3 + classifier + log_softmax
    final_softmax<<<gb, 256, 0, stream>>>(Ubuf, Zbuf, eagg4, rowstart, csrp, consts, out, N);
}

// Round 13
// 202.438 us; speedup vs baseline: 1.0444x; 1.0444x over previous
//
#include <hip/hip_runtime.h>
#include <math.h>

// ---------------------------------------------------------------------------
// GCN (EdgeConv x3 + classifier + log_softmax) on MI355X.
// R13 = R11 verbatim (best measured: 203.6 us). R12's S-precombine regressed
// (+8 us): adding epilogue work to h1_gemm cost more than the L2-resident
// traffic it saved in gather2. Structure:
//  - split CSR build: build_count returns pos (coalesced), csr_scatter uses
//    rowstart[dst]+pos[e] (plain loads; NEVER atomic-return + dependent
//    scattered store — R9 lesson).
//  - packed CSR uint2/edge {bf16 ea0|ea1, bf16 ea2|src<<16}.
//  - h1_gemm: fused layer-1 (8 lanes/node edge agg + 10->128 matvec, h1 bf16
//    in LDS stride-144) + layer-2 MFMA GEMM (16x16x32_bf16, B from global
//    W2bf) -> AI2 fp32 + AJ2 fp16.
//  - gather2: 8 lanes/node, 8 nodes/wave, v_pk_add_f16 dual accumulators,
//    fused relu + collapsed-layer-3 U/Z projection.
//  - final_softmax: collapsed layer3+classifier over Z (16 B/edge).
// Harness d_ws 256MiB poison fill (~45us, 75% HBM peak) is fixed cost and
// the only dispatch at a hardware roofline.
// ---------------------------------------------------------------------------

static inline size_t align256(size_t x) { return (x + 255) & ~size_t(255); }

typedef unsigned short ushort_t;
using frag8  = __attribute__((ext_vector_type(8))) short;     // 8 bf16 (4 VGPR)
using f32x4v = __attribute__((ext_vector_type(4))) float;     // 4 fp32 acc
using half8  = __attribute__((ext_vector_type(8))) _Float16;  // 8 fp16

__device__ inline unsigned short f2bf(float f) {
    unsigned u = __float_as_uint(f);
    unsigned r = (u + 0x7fffu + ((u >> 16) & 1u)) >> 16;
    return (unsigned short)r;
}
__device__ inline float bflo(unsigned u) { return __uint_as_float(u << 16); }
__device__ inline float bfhi(unsigned u) { return __uint_as_float(u & 0xffff0000u); }

// ---- CSR build ------------------------------------------------------------

__global__ __launch_bounds__(256) void build_count(
    const int* __restrict__ ei, int* __restrict__ count,
    int* __restrict__ pos, int E)
{
    int e4 = (blockIdx.x * 256 + threadIdx.x) * 4;
    if (e4 >= E) return;
    if (e4 + 3 < E) {
        int4 d = *(const int4*)(ei + E + e4);
        int4 po;
        po.x = atomicAdd(&count[d.x], 1);
        po.y = atomicAdd(&count[d.y], 1);
        po.z = atomicAdd(&count[d.z], 1);
        po.w = atomicAdd(&count[d.w], 1);
        *(int4*)(pos + e4) = po;
    } else {
        for (int e = e4; e < E; ++e)
            pos[e] = atomicAdd(&count[ei[E + e]], 1);
    }
}

__global__ __launch_bounds__(256) void scan_pass1(
    const int* __restrict__ count, int* __restrict__ rowstart,
    int* __restrict__ bsum, int n)
{
    __shared__ int sh[256];
    const int tid = threadIdx.x;
    const int base = blockIdx.x * 1024 + tid * 4;
    int v0 = 0, v1 = 0, v2 = 0, v3 = 0;
    if (base + 3 < n) {
        int4 c = *(const int4*)(count + base);
        v0 = c.x; v1 = c.y; v2 = c.z; v3 = c.w;
    } else {
        if (base + 0 < n) v0 = count[base + 0];
        if (base + 1 < n) v1 = count[base + 1];
        if (base + 2 < n) v2 = count[base + 2];
        if (base + 3 < n) v3 = count[base + 3];
    }
    int tsum = v0 + v1 + v2 + v3;
    sh[tid] = tsum;
    __syncthreads();
    for (int off = 1; off < 256; off <<= 1) {
        int t = (tid >= off) ? sh[tid - off] : 0;
        __syncthreads();
        sh[tid] += t;
        __syncthreads();
    }
    int excl = sh[tid] - tsum;
    int p0 = excl + v0, p1 = p0 + v1, p2 = p1 + v2, p3 = p2 + v3;
    if (base + 0 < n) rowstart[base + 1] = p0;
    if (base + 1 < n) rowstart[base + 2] = p1;
    if (base + 2 < n) rowstart[base + 3] = p2;
    if (base + 3 < n) rowstart[base + 4] = p3;
    if (tid == 255) bsum[blockIdx.x] = sh[255];
}

// mid_fused: block 0 = scan_pass2; block 1 = collapsed layer-3 prep;
// blocks 2-5 = W2 -> bf16 [col][k] global buffer (32 KB).
__global__ __launch_bounds__(256) void mid_fused(
    const int* __restrict__ bsum, int* __restrict__ bexcl, int nb,
    const float* __restrict__ W3, const float* __restrict__ b3,
    const float* __restrict__ Wc, const float* __restrict__ bc,
    float* __restrict__ AB, float* __restrict__ consts,
    const float* __restrict__ W2, ushort_t* __restrict__ W2bf)
{
    const int t = threadIdx.x;
    if (blockIdx.x == 0) {
        if (t < 64) {
            int own = (t < nb) ? bsum[t] : 0;
            int x = own;
            for (int off = 1; off < 64; off <<= 1) {
                int s = __shfl_up(x, off);
                if (t >= off) x += s;
            }
            bexcl[t] = x - own;
        }
    } else if (blockIdx.x == 1) {
        for (int idx = t; idx < 512; idx += 256) {
            int j = idx >> 6, k = idx & 63;
            int jj = j & 3;
            int base = (j >= 4) ? 64 : 0;
            float s = 0.f;
            #pragma unroll
            for (int c = 0; c < 32; ++c)
                s += Wc[jj * 32 + c] * W3[c * 131 + base + k];
            AB[idx] = s;
        }
        if (t < 4) {
            float db = 0.f;
            for (int c = 0; c < 32; ++c) db += Wc[t * 32 + c] * b3[c];
            consts[t] = db;
            consts[4 + t] = bc[t];
            for (int q = 0; q < 3; ++q) {
                float s = 0.f;
                for (int c = 0; c < 32; ++c) s += Wc[t * 32 + c] * W3[c * 131 + 128 + q];
                consts[8 + t * 3 + q] = s;
            }
        }
    } else {
        int i0 = (blockIdx.x - 2) * 4096 + t;
        int i1 = (blockIdx.x - 1) * 4096;
        for (int idx = i0; idx < i1; idx += 256) {
            int jg = idx >> 7, k = idx & 127;
            float w = (jg < 64) ? W2[jg * 259 + k] : W2[(jg - 64) * 259 + 128 + k];
            W2bf[idx] = f2bf(w);
        }
    }
}

// pass3: finalize rowstart; also emit xpad float4 table
__global__ __launch_bounds__(256) void scan_pass3(
    int* __restrict__ rowstart, const int* __restrict__ bexcl,
    const float* __restrict__ x, float4* __restrict__ xpad, int n)
{
    int j = blockIdx.x * 256 + threadIdx.x;
    if (j > n) return;
    if (j == 0) {
        rowstart[0] = 0;
    } else {
        int b = (j - 1) >> 10;
        if (b > 0) rowstart[j] += bexcl[b];
    }
    if (j < n)
        xpad[j] = make_float4(x[j * 3], x[j * 3 + 1], x[j * 3 + 2], 0.f);
}

// scatter packed edge record: {bf16 e0 | bf16 e1 << 16, bf16 e2 | src << 16}
__global__ __launch_bounds__(256) void csr_scatter(
    const int* __restrict__ ei, const float* __restrict__ ea,
    const int* __restrict__ pos, const int* __restrict__ rowstart,
    uint2* __restrict__ csrp, int E)
{
    int e4 = (blockIdx.x * 256 + threadIdx.x) * 4;
    if (e4 >= E) return;
    if (e4 + 3 < E) {
        int4 s = *(const int4*)(ei + e4);
        int4 d = *(const int4*)(ei + E + e4);
        int4 po = *(const int4*)(pos + e4);
        float4 a = *(const float4*)(ea + (size_t)e4 * 3);
        float4 b = *(const float4*)(ea + (size_t)e4 * 3 + 4);
        float4 c = *(const float4*)(ea + (size_t)e4 * 3 + 8);
        float ev[12] = { a.x, a.y, a.z, a.w, b.x, b.y, b.z, b.w, c.x, c.y, c.z, c.w };
        int sv[4] = { s.x, s.y, s.z, s.w };
        int dv[4] = { d.x, d.y, d.z, d.w };
        int pv[4] = { po.x, po.y, po.z, po.w };
        #pragma unroll
        for (int r = 0; r < 4; ++r) {
            uint2 p;
            p.x = (unsigned)f2bf(ev[r * 3 + 0]) | ((unsigned)f2bf(ev[r * 3 + 1]) << 16);
            p.y = (unsigned)f2bf(ev[r * 3 + 2]) | ((unsigned)sv[r] << 16);
            csrp[rowstart[dv[r]] + pv[r]] = p;
        }
    } else {
        for (int e = e4; e < E; ++e) {
            uint2 p;
            p.x = (unsigned)f2bf(ea[e * 3 + 0]) | ((unsigned)f2bf(ea[e * 3 + 1]) << 16);
            p.y = (unsigned)f2bf(ea[e * 3 + 2]) | ((unsigned)ei[e] << 16);
            csrp[rowstart[ei[E + e]] + pos[e]] = p;
        }
    }
}

// ---- fused layer-1 + layer-2 GEMM -----------------------------------------
// Block = 64 nodes. Phase 1: 8 lanes/node edge aggregation + 10->128 matvec,
// h1 (bf16) written to LDS tile (row stride 144 ushorts = 288 B).
// Phase 2: MFMA 16x16x32_bf16, A-frags from LDS, B-frags from global W2bf.

__global__ __launch_bounds__(256) void h1_gemm(
    const float4* __restrict__ xpad, const float* __restrict__ W1,
    const float* __restrict__ b1, const int* __restrict__ rowstart,
    const uint2* __restrict__ csrp, float4* __restrict__ eagg4,
    const ushort_t* __restrict__ W2bf,
    float* __restrict__ AI2, _Float16* __restrict__ AJ2, int n_nodes)
{
    constexpr int HS = 144;                 // LDS h1 row stride (ushorts)
    __shared__ float sM[10 * 128];
    __shared__ ushort_t sH[64 * HS];

    const int tid = threadIdx.x;
    for (int t = tid; t < 1280; t += 256) {
        int k = t >> 7, c = t & 127;
        sM[t] = (k < 9) ? W1[c * 9 + k] : b1[c];
    }
    __syncthreads();

    const int base = blockIdx.x * 64;
    const int wave = tid >> 6, wl = tid & 63;
    const int grp = wl >> 3, ch8 = wl & 7;

    // ---- phase 1: two passes of 32 nodes ----
    #pragma unroll
    for (int pass = 0; pass < 2; ++pass) {
        int nl = pass * 32 + wave * 8 + grp;
        int n = base + nl;
        float hv[16];
        if (n < n_nodes) {
            int s0 = rowstart[n], s1 = rowstart[n + 1];
            float xx = 0.f, xy = 0.f, xz = 0.f, ex = 0.f, ey = 0.f, ez = 0.f;
            for (int i = s0 + ch8; i < s1; i += 8) {
                uint2 p = csrp[i];
                int s = (int)(p.y >> 16);
                ex += bflo(p.x); ey += bfhi(p.x); ez += bflo(p.y);
                float4 xv = xpad[s];
                xx += xv.x; xy += xv.y; xz += xv.z;
            }
            #pragma unroll
            for (int off = 1; off < 8; off <<= 1) {
                xx += __shfl_xor(xx, off); xy += __shfl_xor(xy, off); xz += __shfl_xor(xz, off);
                ex += __shfl_xor(ex, off); ey += __shfl_xor(ey, off); ez += __shfl_xor(ez, off);
            }
            float deg = (float)(s1 - s0 + 1);
            float4 xs = xpad[n];
            float v[10] = { deg * xs.x, deg * xs.y, deg * xs.z,
                            xs.x + xx, xs.y + xy, xs.z + xz,
                            ex, ey, ez, deg };
            #pragma unroll
            for (int q = 0; q < 16; ++q) {
                int c = ch8 * 16 + q;
                float h = 0.f;
                #pragma unroll
                for (int k = 0; k < 10; ++k) h += v[k] * sM[k * 128 + c];
                hv[q] = fmaxf(h, 0.f);
            }
            if (ch8 == 0) eagg4[n] = make_float4(ex, ey, ez, 0.f);
        } else {
            #pragma unroll
            for (int q = 0; q < 16; ++q) hv[q] = 0.f;
        }
        #pragma unroll
        for (int g = 0; g < 2; ++g) {
            uint4 u;
            u.x = (unsigned)f2bf(hv[g * 8 + 0]) | ((unsigned)f2bf(hv[g * 8 + 1]) << 16);
            u.y = (unsigned)f2bf(hv[g * 8 + 2]) | ((unsigned)f2bf(hv[g * 8 + 3]) << 16);
            u.z = (unsigned)f2bf(hv[g * 8 + 4]) | ((unsigned)f2bf(hv[g * 8 + 5]) << 16);
            u.w = (unsigned)f2bf(hv[g * 8 + 6]) | ((unsigned)f2bf(hv[g * 8 + 7]) << 16);
            *(uint4*)(sH + nl * HS + ch8 * 16 + g * 8) = u;
        }
    }
    __syncthreads();

    // ---- phase 2: MFMA ----
    const int m = wl & 15, quad = wl >> 4;

    frag8 a[4];
    #pragma unroll
    for (int ks = 0; ks < 4; ++ks)
        a[ks] = *(const frag8*)(sH + (wave * 16 + m) * HS + ks * 32 + quad * 8);

    f32x4v acc[8];
    #pragma unroll
    for (int t = 0; t < 8; ++t) acc[t] = (f32x4v)(0.f);

    #pragma unroll
    for (int t = 0; t < 8; ++t) {
        #pragma unroll
        for (int ks = 0; ks < 4; ++ks) {
            frag8 b = *(const frag8*)(W2bf + (t * 16 + m) * 128 + ks * 32 + quad * 8);
            acc[t] = __builtin_amdgcn_mfma_f32_16x16x32_bf16(a[ks], b, acc[t], 0, 0, 0);
        }
    }

    #pragma unroll
    for (int reg = 0; reg < 4; ++reg) {
        int grow = base + wave * 16 + quad * 4 + reg;
        if (grow >= n_nodes) continue;
        #pragma unroll
        for (int t = 0; t < 4; ++t)
            AI2[(size_t)grow * 64 + t * 16 + m] = acc[t][reg];
        #pragma unroll
        for (int t = 4; t < 8; ++t)
            AJ2[(size_t)grow * 64 + (t - 4) * 16 + m] = (_Float16)acc[t][reg];
    }
}

// ---- layer-2 gather: 8 lanes/node, 8 nodes/wave, fp16 packed accumulate ---

__global__ __launch_bounds__(256) void gather2(
    const float* __restrict__ AI2, const _Float16* __restrict__ AJ2,
    const float* __restrict__ W2, const float* __restrict__ b2,
    const float4* __restrict__ eagg4, const int* __restrict__ rowstart,
    const uint2* __restrict__ csrp, const float* __restrict__ AB,
    float* __restrict__ U, float* __restrict__ Z, int n_nodes)
{
    __shared__ float sAB[512];
    __shared__ float sWe[192];
    const int tid = threadIdx.x;
    for (int t = tid; t < 512; t += 256) sAB[t] = AB[t];
    for (int t = tid; t < 192; t += 256) {
        int c = t / 3, q = t % 3;
        sWe[t] = W2[c * 259 + 256 + q];
    }
    __syncthreads();

    int wl = tid & 63;
    int grp = wl >> 3, ch8 = wl & 7;
    int n = blockIdx.x * 32 + (tid >> 6) * 8 + grp;
    if (n >= n_nodes) return;

    int s0 = rowstart[n], s1 = rowstart[n + 1];

    half8 hacc0 = (half8)(_Float16)0.f;
    half8 hacc1 = (half8)(_Float16)0.f;
    for (int base = s0; base < s1; base += 8) {
        int j = base + ch8;
        if (j >= s1) j = s1 - 1;            // clamped lanes never consumed
        int myidx = (int)(csrp[j].y >> 16);
        int cnt = s1 - base; if (cnt > 8) cnt = 8;
        #pragma unroll
        for (int k = 0; k < 8; ++k) {
            int s = __shfl(myidx, grp * 8 + k);
            if (k < cnt) {
                half8 v = *(const half8*)(AJ2 + (size_t)s * 64 + ch8 * 8);
                if (k & 1) hacc1 += v; else hacc0 += v;
            }
        }
    }
    float acc[8];
    #pragma unroll
    for (int q = 0; q < 8; ++q) acc[q] = (float)hacc0[q] + (float)hacc1[q];

    float deg = (float)(s1 - s0 + 1);
    float4 e4 = eagg4[n];
    const float* aip = AI2 + (size_t)n * 64 + ch8 * 8;
    float4 aiA = *(const float4*)(aip);
    float4 aiB = *(const float4*)(aip + 4);
    half8 su = *(const half8*)(AJ2 + (size_t)n * 64 + ch8 * 8);
    float4 bA = *(const float4*)(b2 + ch8 * 8);
    float4 bB = *(const float4*)(b2 + ch8 * 8 + 4);
    float av[8] = { aiA.x, aiA.y, aiA.z, aiA.w, aiB.x, aiB.y, aiB.z, aiB.w };
    float bv[8] = { bA.x, bA.y, bA.z, bA.w, bB.x, bB.y, bB.z, bB.w };
    float r[8];
    #pragma unroll
    for (int q = 0; q < 8; ++q) {
        int c = ch8 * 8 + q;
        float we = sWe[c * 3] * e4.x + sWe[c * 3 + 1] * e4.y + sWe[c * 3 + 2] * e4.z;
        r[q] = fmaxf(deg * (av[q] + bv[q]) + (float)su[q] + we + acc[q], 0.f);
    }
    float pj[8];
    #pragma unroll
    for (int j = 0; j < 8; ++j) {
        float4 wA = *(const float4*)(sAB + j * 64 + ch8 * 8);
        float4 wB = *(const float4*)(sAB + j * 64 + ch8 * 8 + 4);
        pj[j] = r[0] * wA.x + r[1] * wA.y + r[2] * wA.z + r[3] * wA.w
              + r[4] * wB.x + r[5] * wB.y + r[6] * wB.z + r[7] * wB.w;
    }
    #pragma unroll
    for (int off = 1; off < 8; off <<= 1)
        #pragma unroll
        for (int j = 0; j < 8; ++j) pj[j] += __shfl_xor(pj[j], off);

    if (ch8 == 0) {
        *(float4*)(U + (size_t)n * 4) = make_float4(pj[0], pj[1], pj[2], pj[3]);
        *(float4*)(Z + (size_t)n * 4) = make_float4(pj[4], pj[5], pj[6], pj[7]);
    }
}

// ---- final: 8 lanes/node, 8 nodes/wave, sum Z[src] + log_softmax ----------

__global__ __launch_bounds__(256) void final_softmax(
    const float* __restrict__ U, const float* __restrict__ Z,
    const float4* __restrict__ eagg4, const int* __restrict__ rowstart,
    const uint2* __restrict__ csrp, const float* __restrict__ consts,
    float* __restrict__ out, int n_nodes)
{
    int wl = threadIdx.x & 63;
    int grp = wl >> 3, ch8 = wl & 7;
    int n = blockIdx.x * 32 + (threadIdx.x >> 6) * 8 + grp;
    if (n >= n_nodes) return;

    int s0 = rowstart[n], s1 = rowstart[n + 1];
    float ax = 0.f, ay = 0.f, az = 0.f, aw = 0.f;
    for (int i = s0 + ch8; i < s1; i += 8) {
        int s = (int)(csrp[i].y >> 16);
        float4 z = *(const float4*)(Z + (size_t)s * 4);
        ax += z.x; ay += z.y; az += z.z; aw += z.w;
    }
    #pragma unroll
    for (int off = 1; off < 8; off <<= 1) {
        ax += __shfl_xor(ax, off); ay += __shfl_xor(ay, off);
        az += __shfl_xor(az, off); aw += __shfl_xor(aw, off);
    }
    if (ch8 != 0) return;

    float deg = (float)(s1 - s0 + 1);
    float4 u = *(const float4*)(U + (size_t)n * 4);
    float4 zs = *(const float4*)(Z + (size_t)n * 4);   // self-loop term
    float4 e4 = eagg4[n];
    float av[4] = { ax + zs.x, ay + zs.y, az + zs.z, aw + zs.w };
    float uv[4] = { u.x, u.y, u.z, u.w };
    float lg[4];
    #pragma unroll
    for (int j = 0; j < 4; ++j) {
        lg[j] = deg * (uv[j] + consts[j]) + av[j] + consts[4 + j]
              + consts[8 + j * 3] * e4.x + consts[9 + j * 3] * e4.y
              + consts[10 + j * 3] * e4.z;
    }
    float m = fmaxf(fmaxf(lg[0], lg[1]), fmaxf(lg[2], lg[3]));
    float lse = logf(expf(lg[0] - m) + expf(lg[1] - m) + expf(lg[2] - m) + expf(lg[3] - m));
    *(float4*)(out + (size_t)n * 4) =
        make_float4(lg[0] - m - lse, lg[1] - m - lse, lg[2] - m - lse, lg[3] - m - lse);
}

// ---------------------------------------------------------------------------

extern "C" void kernel_launch(void* const* d_in, const int* in_sizes, int n_in,
                              void* d_out, int out_size, void* d_ws, size_t ws_size,
                              hipStream_t stream)
{
    const float* x    = (const float*)d_in[0];
    const int*   ei   = (const int*)  d_in[1];
    const float* ea   = (const float*)d_in[2];
    const float* W1   = (const float*)d_in[3];
    const float* b1   = (const float*)d_in[4];
    const float* W2   = (const float*)d_in[5];
    const float* b2   = (const float*)d_in[6];
    const float* W3   = (const float*)d_in[7];
    const float* b3   = (const float*)d_in[8];
    const float* Wc   = (const float*)d_in[9];
    const float* bc   = (const float*)d_in[10];
    float* out = (float*)d_out;

    const int N = in_sizes[0] / 3;
    const int E = in_sizes[1] / 2;

    char* ws = (char*)d_ws;
    size_t off = 0;
    int*    count    = (int*)(ws + off);            off = align256(off + (size_t)N * 4);
    int*    pos      = (int*)(ws + off);            off = align256(off + (size_t)E * 4);
    int*    rowstart = (int*)(ws + off);            off = align256(off + (size_t)(N + 1) * 4);
    uint2*  csrp     = (uint2*)(ws + off);          off = align256(off + (size_t)E * 8);
    int*    bsum     = (int*)(ws + off);            off = align256(off + 256);
    int*    bexcl    = (int*)(ws + off);            off = align256(off + 256);
    float*  AB       = (float*)(ws + off);          off = align256(off + 512 * 4);
    float*  consts   = (float*)(ws + off);          off = align256(off + 32 * 4);
    ushort_t* W2bf   = (ushort_t*)(ws + off);       off = align256(off + 128 * 128 * 2);
    float4* xpad     = (float4*)(ws + off);         off = align256(off + (size_t)N * 16);
    float4* eagg4    = (float4*)(ws + off);         off = align256(off + (size_t)N * 16);
    float*  AI2      = (float*)(ws + off);          off = align256(off + (size_t)N * 64 * 4);
    _Float16* AJ2    = (_Float16*)(ws + off);       off = align256(off + (size_t)N * 64 * 2);
    float*  Ubuf     = (float*)(ws + off);          off = align256(off + (size_t)N * 16);
    float*  Zbuf     = (float*)(ws + off);          off = align256(off + (size_t)N * 16);
    (void)ws_size;

    hipMemsetAsync(count, 0, (size_t)N * 4, stream);

    const int eb4 = ((E + 3) / 4 + 255) / 256;
    build_count<<<eb4, 256, 0, stream>>>(ei, count, pos, E);

    const int nb1 = (N + 1023) / 1024;
    scan_pass1<<<nb1, 256, 0, stream>>>(count, rowstart, bsum, N);
    mid_fused<<<6, 256, 0, stream>>>(bsum, bexcl, nb1, W3, b3, Wc, bc, AB, consts, W2, W2bf);
    scan_pass3<<<(N + 1 + 255) / 256, 256, 0, stream>>>(rowstart, bexcl, x, xpad, N);
    csr_scatter<<<eb4, 256, 0, stream>>>(ei, ea, pos, rowstart, csrp, E);

    // fused layer-1 (edge agg + matvec, h1 in LDS) + layer-2 MFMA GEMM
    h1_gemm<<<(N + 63) / 64, 256, 0, stream>>>(xpad, W1, b1, rowstart, csrp,
                                               eagg4, W2bf, AI2, AJ2, N);

    // layer-2 gather + relu + U/Z projection
    const int gb = (N + 31) / 32;
    gather2<<<gb, 256, 0, stream>>>(AI2, AJ2, W2, b2, eagg4, rowstart, csrp, AB, Ubuf, Zbuf, N);

    // collapsed layer 3 + classifier + log_softmax
    final_softmax<<<gb, 256, 0, stream>>>(Ubuf, Zbuf, eagg4, rowstart, csrp, consts, out, N);
}